// Round 4
// baseline (140.400 us; speedup 1.0000x reference)
//
#include <hip/hip_runtime.h>
#include <math.h>

// B=16384 rows, C=1000 cols, fp32 -> 16384 fp32.
//
// R1-R3 all landed 42-45 us regardless of occupancy/VALU changes. Invariant:
// ~256 MB of demand vector-load traffic (inputs read twice: pass1 + compiler's
// pass2 reload; L3-resident, FETCH~0 on replays) at ~10 B/cyc/CU — the CU
// vector-load return-path ceiling (m13). R4 removes the second global read:
// stage each row global->LDS ONCE via global_load_lds (>=21 B/cyc/CU on the
// m97 GEMM), then both passes read LDS (69 TB/s ceiling, ~5 us total).
// One wave per row, 4 rows/block, 32 KB LDS -> 5 blocks/CU.

constexpr int kC  = 1000;
constexpr int kNV = kC / 4;          // 250 float4 per row
constexpr int kRowsPerBlock = 4;
constexpr int kTailLanes = kNV - 192;  // 58 active lanes in chunk 3

#define GLDS16(gp, lp)                                                         \
  __builtin_amdgcn_global_load_lds(                                            \
      (const __attribute__((address_space(1))) void*)(gp),                     \
      (__attribute__((address_space(3))) void*)(lp), 16, 0, 0)

__global__ __launch_bounds__(256) void netsat_kernel(
    const float* __restrict__ y1, const float* __restrict__ y2,
    float* __restrict__ out, int nrows)
{
    __shared__ float4 buf[kRowsPerBlock][2][256];   // 32 KB/block

    const int lane = threadIdx.x & 63;
    const int wave = threadIdx.x >> 6;
    const int row0 = blockIdx.x * kRowsPerBlock + wave;
    const bool valid = row0 < nrows;
    const int row = valid ? row0 : (nrows - 1);     // grid is exact; safety

    const float4* r1 = reinterpret_cast<const float4*>(y1) + (size_t)row * kNV;
    const float4* r2 = reinterpret_cast<const float4*>(y2) + (size_t)row * kNV;

    // ---- stage this wave's row: global -> LDS, 16 B/lane, no VGPR trip ----
    // LDS dest is wave-uniform base + lane*16 (hardware rule), so chunk c of
    // input t lands contiguous at buf[wave][t][c*64 .. c*64+63].
#pragma unroll
    for (int c = 0; c < 3; ++c) {
        GLDS16(r1 + lane + 64 * c, &buf[wave][0][c * 64]);
        GLDS16(r2 + lane + 64 * c, &buf[wave][1][c * 64]);
    }
    if (lane < kTailLanes) {
        GLDS16(r1 + lane + 192, &buf[wave][0][192]);
        GLDS16(r2 + lane + 192, &buf[wave][1][192]);
    }
    __syncthreads();   // compiler emits s_waitcnt vmcnt(0) before s_barrier

    // ---- pass 1: branchless per-lane top-2 for both inputs, from LDS ----
    const float4 ninf4 = make_float4(-INFINITY, -INFINITY, -INFINITY, -INFINITY);
    float m1 = -INFINITY, m2 = -INFINITY;
    float n1 = -INFINITY, n2 = -INFINITY;
#pragma unroll
    for (int c = 0; c < 4; ++c) {
        const int vi0 = lane + 64 * c;
        const bool ok = vi0 < kNV;
        const int vi = ok ? vi0 : 0;
        float4 va = buf[wave][0][vi];
        float4 vb = buf[wave][1][vi];
        if (!ok) { va = ninf4; vb = ninf4; }
        const float* av = reinterpret_cast<const float*>(&va);
        const float* bv = reinterpret_cast<const float*>(&vb);
#pragma unroll
        for (int k = 0; k < 4; ++k) {
            const float v = av[k];
            m2 = fmaxf(m2, fminf(m1, v)); m1 = fmaxf(m1, v);
            const float w = bv[k];
            n2 = fmaxf(n2, fminf(n1, w)); n1 = fmaxf(n1, w);
        }
    }

    // ---- wave butterfly: merge (top1, top2) pairs; all lanes converge ----
#pragma unroll
    for (int off = 32; off > 0; off >>= 1) {
        const float o1 = __shfl_xor(m1, off, 64);
        const float o2 = __shfl_xor(m2, off, 64);
        const float p1 = __shfl_xor(n1, off, 64);
        const float p2 = __shfl_xor(n2, off, 64);
        m2 = fmaxf(fminf(m1, o1), fmaxf(m2, o2));
        m1 = fmaxf(m1, o1);
        n2 = fmaxf(fminf(n1, p1), fmaxf(n2, p2));
        n1 = fmaxf(n1, p1);
    }

    // ---- pass 2: max_j min(v - loo1, w - loo2), from LDS ----
    // loo(v) = (v==m1) ? m2 : m1 — tie-safe (duplicated max => m2==m1).
    float best = -INFINITY;
#pragma unroll
    for (int c = 0; c < 4; ++c) {
        const int vi0 = lane + 64 * c;
        const bool ok = vi0 < kNV;
        const int vi = ok ? vi0 : 0;
        float4 va = buf[wave][0][vi];
        float4 vb = buf[wave][1][vi];
        if (!ok) { va = ninf4; vb = ninf4; }
        const float* av = reinterpret_cast<const float*>(&va);
        const float* bv = reinterpret_cast<const float*>(&vb);
#pragma unroll
        for (int k = 0; k < 4; ++k) {
            const float v = av[k];
            const float w = bv[k];
            const float l1 = (v == m1) ? m2 : m1;
            const float l2 = (w == n1) ? n2 : n1;
            best = fmaxf(best, fminf(v - l1, w - l2));
        }
    }
#pragma unroll
    for (int off = 32; off > 0; off >>= 1)
        best = fmaxf(best, __shfl_xor(best, off, 64));

    if (lane == 0 && valid) out[row0] = best;
}

extern "C" void kernel_launch(void* const* d_in, const int* in_sizes, int n_in,
                              void* d_out, int out_size, void* d_ws, size_t ws_size,
                              hipStream_t stream) {
    const float* y1 = (const float*)d_in[0];
    const float* y2 = (const float*)d_in[1];
    float* out = (float*)d_out;
    const int nrows = out_size;  // 16384
    const int blocks = (nrows + kRowsPerBlock - 1) / kRowsPerBlock;  // 4096
    netsat_kernel<<<blocks, 256, 0, stream>>>(y1, y2, out, nrows);
}